// Round 3
// baseline (227.485 us; speedup 1.0000x reference)
//
#include <hip/hip_runtime.h>

#define THREADS 256

typedef __attribute__((ext_vector_type(8))) short bf16x8;
typedef __attribute__((ext_vector_type(4))) float f32x4;

// fp32 -> bf16 with round-to-nearest-even (matches HW convert)
__device__ inline unsigned short f2bf(float f) {
    union { float f; unsigned int u; } v; v.f = f;
    unsigned int r = v.u + 0x7fffu + ((v.u >> 16) & 1u);
    return (unsigned short)(r >> 16);
}

// ---------------------------------------------------------------------------
// Kernel A (v3): in-side contraction, ONE WAVE PER ROW, zero block barriers.
//   x[N,4096] -> u3b[N,512] (bf16); core conversion folded into blocks 0..255.
//
//   Per row (d,e,f in 16):
//     u1[d,e,n6] = sum_f x[d,e,f] f5[f,n6]
//     u2[d,m,n6] = sum_e u1[d,e,n6] f4[e,m]
//     u3[l,m,n6] = sum_d u2[d,m,n6] f3[d,l]
//
//   Lane L = 4a+b owns de in [4L,4L+4) => d=a, e in [4b,4b+4).
//   - u1+psum: lane-local (x chunk is lane-contiguous 64 floats).
//   - e-contraction: 4-lane __shfl_xor reduce (b-groups) -> full u2[d=a,:,:]
//     replicated; lane b writes m-slice {2b,2b+1} to wave-local LDS.
//   - d-contraction: lane owns mn=lane, reads u2s[d*68+mn] (2-way banks, free).
//   Sync: wave-internal only -> s_waitcnt lgkmcnt(0) + sched_barrier (rule #18).
//   Grid N/4=1024 blocks x 4 waves = 4 waves/SIMD; ~110 VGPR live (<128 cap).
// ---------------------------------------------------------------------------
__global__ __launch_bounds__(THREADS, 4) void k_in_contract3(
    const float* __restrict__ x,
    const float* __restrict__ f3, const float* __restrict__ f4,
    const float* __restrict__ f5, const float* __restrict__ core,
    unsigned short* __restrict__ u3b, unsigned short* __restrict__ coreb,
    int N)
{
    const int t    = threadIdx.x;
    const int wave = t >> 6;
    const int lane = t & 63;
    const int row  = blockIdx.x * 4 + wave;
    const int a = lane >> 2;     // d
    const int b = lane & 3;      // e-quarter

    __shared__ float u2s[4][16 * 68];   // per-wave [d][mn], stride 68: 2-way banks

    // ---- folded core fp32->bf16 convert (one float4 per thread, 256 blocks) --
    if (blockIdx.x < 256) {
        const int i = blockIdx.x * THREADS + t;    // 0..65535 float4s
        float4 c = ((const float4*)core)[i];
        ushort4 o;
        o.x = f2bf(c.x); o.y = f2bf(c.y); o.z = f2bf(c.z); o.w = f2bf(c.w);
        ((ushort4*)coreb)[i] = o;
    }

    // ---- u1 + partial u2 (lane-local) -------------------------------------
    const float* xr = x + (size_t)row * 4096 + lane * 64;

    float psum[64];                      // [m][n6] partial over lane's 4 e's
    #pragma unroll
    for (int i = 0; i < 64; ++i) psum[i] = 0.f;

    #pragma unroll
    for (int e0 = 0; e0 < 4; ++e0) {     // e = 4b + e0
        float4 x0 = ((const float4*)xr)[e0*4 + 0];
        float4 x1 = ((const float4*)xr)[e0*4 + 1];
        float4 x2 = ((const float4*)xr)[e0*4 + 2];
        float4 x3 = ((const float4*)xr)[e0*4 + 3];
        float xc[16] = {x0.x,x0.y,x0.z,x0.w, x1.x,x1.y,x1.z,x1.w,
                        x2.x,x2.y,x2.z,x2.w, x3.x,x3.y,x3.z,x3.w};

        float u1[8] = {0.f,0.f,0.f,0.f,0.f,0.f,0.f,0.f};
        #pragma unroll
        for (int f = 0; f < 16; ++f) {
            const float xf = xc[f];
            #pragma unroll
            for (int n6 = 0; n6 < 8; ++n6)
                u1[n6] = fmaf(xf, f5[f*8 + n6], u1[n6]);   // f5 uniform -> s_load
        }

        // f4 row e = 4b+e0 (lane-dependent -> vector loads, L1-broadcast)
        const float4* gp = (const float4*)(f4 + (4*b + e0) * 8);
        float4 g0 = gp[0], g1 = gp[1];
        const float g[8] = {g0.x,g0.y,g0.z,g0.w, g1.x,g1.y,g1.z,g1.w};
        #pragma unroll
        for (int m = 0; m < 8; ++m) {
            const float gm = g[m];
            #pragma unroll
            for (int n6 = 0; n6 < 8; ++n6)
                psum[m*8 + n6] = fmaf(u1[n6], gm, psum[m*8 + n6]);
        }
    }

    // ---- e-contraction finish: 4-lane butterfly reduce over b --------------
    #pragma unroll
    for (int i = 0; i < 64; ++i) {
        psum[i] += __shfl_xor(psum[i], 1, 64);
        psum[i] += __shfl_xor(psum[i], 2, 64);
    }

    // lane b stores m-slice {2b, 2b+1} of u2[d=a] to wave-local LDS
    {
        float* ws = &u2s[wave][0];
        #pragma unroll
        for (int mm = 0; mm < 2; ++mm) {
            const int m = 2*b + mm;
            *(float4*)&ws[a*68 + m*8 + 0] =
                make_float4(psum[m*8+0], psum[m*8+1], psum[m*8+2], psum[m*8+3]);
            *(float4*)&ws[a*68 + m*8 + 4] =
                make_float4(psum[m*8+4], psum[m*8+5], psum[m*8+6], psum[m*8+7]);
        }
    }
    asm volatile("s_waitcnt lgkmcnt(0)" ::: "memory");
    __builtin_amdgcn_sched_barrier(0);

    // ---- u3: lane owns mn = lane; contract over d --------------------------
    {
        const float* ws = &u2s[wave][0];
        float acc[8] = {0.f,0.f,0.f,0.f,0.f,0.f,0.f,0.f};
        #pragma unroll
        for (int d = 0; d < 16; ++d) {
            const float u2v = ws[d*68 + lane];
            #pragma unroll
            for (int l = 0; l < 8; ++l)
                acc[l] = fmaf(u2v, f3[d*8 + l], acc[l]);   // f3 uniform -> s_load
        }
        unsigned short* orow = u3b + (size_t)row * 512;
        #pragma unroll
        for (int l = 0; l < 8; ++l)
            orow[l*64 + lane] = f2bf(acc[l]);
    }
}

// ---------------------------------------------------------------------------
// Kernel B: MFMA GEMM (EXACT revert to round-0 proven version).
//   v[n,p] = sum_q u3[n,q] * core[p,q]
//   Wave tile 32x32 (2x2 of 16x16x32 bf16). Block = 4 waves stacked in m.
//   Grid (4096/128, 512/32) = (32,16) = 512 blocks.
// ---------------------------------------------------------------------------
__global__ __launch_bounds__(THREADS) void k_core_gemm_mfma(
    const unsigned short* __restrict__ u3b,
    const unsigned short* __restrict__ coreb,
    float* __restrict__ v, int N)
{
    const int t    = threadIdx.x;
    const int lane = t & 63;
    const int wave = t >> 6;
    const int m0 = blockIdx.x * 128 + wave * 32;
    const int p0 = blockIdx.y * 32;
    const int lr = lane & 15;
    const int lq = lane >> 4;

    const unsigned short* aptr0 = u3b   + (size_t)(m0 + lr) * 512 + lq * 8;
    const unsigned short* aptr1 = aptr0 + 16 * 512;
    const unsigned short* bptr0 = coreb + (size_t)(p0 + lr) * 512 + lq * 8;
    const unsigned short* bptr1 = bptr0 + 16 * 512;

    f32x4 acc00 = {0.f,0.f,0.f,0.f}, acc01 = {0.f,0.f,0.f,0.f};
    f32x4 acc10 = {0.f,0.f,0.f,0.f}, acc11 = {0.f,0.f,0.f,0.f};

    #pragma unroll
    for (int k0 = 0; k0 < 512; k0 += 32) {
        bf16x8 a0 = *(const bf16x8*)(aptr0 + k0);
        bf16x8 a1 = *(const bf16x8*)(aptr1 + k0);
        bf16x8 b0 = *(const bf16x8*)(bptr0 + k0);
        bf16x8 b1 = *(const bf16x8*)(bptr1 + k0);
        acc00 = __builtin_amdgcn_mfma_f32_16x16x32_bf16(a0, b0, acc00, 0, 0, 0);
        acc01 = __builtin_amdgcn_mfma_f32_16x16x32_bf16(a0, b1, acc01, 0, 0, 0);
        acc10 = __builtin_amdgcn_mfma_f32_16x16x32_bf16(a1, b0, acc10, 0, 0, 0);
        acc11 = __builtin_amdgcn_mfma_f32_16x16x32_bf16(a1, b1, acc11, 0, 0, 0);
    }

    const int row = m0 + lq * 4;
    const int col = p0 + lr;
    #pragma unroll
    for (int r = 0; r < 4; ++r) {
        v[(size_t)(row + r) * 512 + col]           = acc00[r];
        v[(size_t)(row + r) * 512 + col + 16]      = acc01[r];
        v[(size_t)(row + 16 + r) * 512 + col]      = acc10[r];
        v[(size_t)(row + 16 + r) * 512 + col + 16] = acc11[r];
    }
}

// ---------------------------------------------------------------------------
// Kernel C: out-side expansion (EXACT revert to round-0 proven version).
// ---------------------------------------------------------------------------
__global__ __launch_bounds__(THREADS) void k_out_expand(
    const float* __restrict__ v,
    const float* __restrict__ f0, const float* __restrict__ f1,
    const float* __restrict__ f2, const float* __restrict__ bias,
    float* __restrict__ y, int N)
{
    const int n = blockIdx.x;
    const int t = threadIdx.x;

    __shared__ float fs[256];        // f0 [0..128) | f1 [128..256)
    __shared__ float vs[512];
    __shared__ float w1s[128 * 9];   // [a*8+j][k], pad 9
    __shared__ float w2s[256 * 9];   // [a*16+b][k], pad 9

    if (t < 128) { fs[t] = f0[t]; fs[128 + t] = f1[t]; }
    if (t < 128) ((float4*)vs)[t] = ((const float4*)(v + (size_t)n*512))[t];
    __syncthreads();

    // w1 stage: thread -> (a = t>>4, j = (t>>1)&7, h = t&1), k = 4h..4h+3
    {
        const int a = t >> 4, j = (t >> 1) & 7, h = t & 1;
        float fr[8];
        #pragma unroll
        for (int i = 0; i < 8; ++i) fr[i] = fs[a*8 + i];
        float a4[4] = {0.f, 0.f, 0.f, 0.f};
        #pragma unroll
        for (int i = 0; i < 8; ++i) {
            const int base = i*64 + j*8 + h*4;
            #pragma unroll
            for (int q = 0; q < 4; ++q)
                a4[q] = fmaf(vs[base + q], fr[i], a4[q]);
        }
        #pragma unroll
        for (int q = 0; q < 4; ++q) w1s[(a*8 + j)*9 + h*4 + q] = a4[q];
    }
    __syncthreads();

    // w2 stage: thread -> (a = t>>4, b = t&15), all k
    {
        const int a = t >> 4, b = t & 15;
        float fr[8];
        #pragma unroll
        for (int j = 0; j < 8; ++j) fr[j] = fs[128 + b*8 + j];
        float a8[8] = {0.f,0.f,0.f,0.f,0.f,0.f,0.f,0.f};
        #pragma unroll
        for (int j = 0; j < 8; ++j) {
            const int base = (a*8 + j)*9;
            const float fj = fr[j];
            #pragma unroll
            for (int k = 0; k < 8; ++k)
                a8[k] = fmaf(w1s[base + k], fj, a8[k]);
        }
        #pragma unroll
        for (int k = 0; k < 8; ++k) w2s[(a*16 + b)*9 + k] = a8[k];
    }
    __syncthreads();

    // y stage: thread -> (a = t>>4, b = t&15), c = 0..15
    {
        const int a = t >> 4, b = t & 15;
        float wr[8];
        #pragma unroll
        for (int k = 0; k < 8; ++k) wr[k] = w2s[(a*16 + b)*9 + k];

        const int obase = a*256 + b*16;   // == t*16
        float4 b4[4];
        {
            const float4* bp = (const float4*)(bias + obase);
            b4[0] = bp[0]; b4[1] = bp[1]; b4[2] = bp[2]; b4[3] = bp[3];
        }
        float yv[16];
        #pragma unroll
        for (int q = 0; q < 4; ++q) {
            yv[q*4+0] = b4[q].x; yv[q*4+1] = b4[q].y;
            yv[q*4+2] = b4[q].z; yv[q*4+3] = b4[q].w;
        }
        #pragma unroll
        for (int c = 0; c < 16; ++c) {
            float s = yv[c];
            #pragma unroll
            for (int k = 0; k < 8; ++k)
                s = fmaf(wr[k], f2[c*8 + k], s);   // f2 lane-uniform -> s_load
            yv[c] = s;
        }
        float4* o = (float4*)(y + (size_t)n*4096 + obase);
        #pragma unroll
        for (int q = 0; q < 4; ++q)
            o[q] = make_float4(yv[q*4+0], yv[q*4+1], yv[q*4+2], yv[q*4+3]);
    }
}

// ---------------------------------------------------------------------------
extern "C" void kernel_launch(void* const* d_in, const int* in_sizes, int n_in,
                              void* d_out, int out_size, void* d_ws, size_t ws_size,
                              hipStream_t stream)
{
    const float* x    = (const float*)d_in[0];
    const float* core = (const float*)d_in[1];
    const float* f0   = (const float*)d_in[2];
    const float* f1   = (const float*)d_in[3];
    const float* f2   = (const float*)d_in[4];
    const float* f3   = (const float*)d_in[5];
    const float* f4   = (const float*)d_in[6];
    const float* f5   = (const float*)d_in[7];
    const float* bias = (const float*)d_in[8];
    float* y = (float*)d_out;

    const int N = in_sizes[0] / 4096;

    // workspace: u3b bf16 [N,512] (4MB) | coreb bf16 [512,512] (0.5MB)
    //          | v fp32 [N,512] (8MB)
    unsigned short* u3b   = (unsigned short*)d_ws;
    unsigned short* coreb = u3b + (size_t)N * 512;
    float*          v     = (float*)(coreb + 512 * 512);

    k_in_contract3<<<N / 4, THREADS, 0, stream>>>(x, f3, f4, f5, core,
                                                  u3b, coreb, N);
    dim3 gb(N / 128, 512 / 32);
    k_core_gemm_mfma<<<gb, THREADS, 0, stream>>>(u3b, coreb, v, N);
    k_out_expand<<<N, THREADS, 0, stream>>>(v, f0, f1, f2, bias, y, N);
}

// Round 4
// 163.187 us; speedup vs baseline: 1.3940x; 1.3940x over previous
//
#include <hip/hip_runtime.h>

#define THREADS 256

typedef __attribute__((ext_vector_type(8))) short bf16x8;
typedef __attribute__((ext_vector_type(4))) float f32x4;

// fp32 -> bf16 with round-to-nearest-even (matches HW convert)
__device__ inline unsigned short f2bf(float f) {
    union { float f; unsigned int u; } v; v.f = f;
    unsigned int r = v.u + 0x7fffu + ((v.u >> 16) & 1u);
    return (unsigned short)(r >> 16);
}

// ---------------------------------------------------------------------------
// Kernel A: in-side contraction  x[N,4096] -> u3b[N,512] (bf16)
//   (EXACT round-0 proven version; ~21 us inferred. R3's wave-per-row
//    rewrite hit rule #20 scratch spills: psum[] runtime-indexed -> 87 us.)
// ---------------------------------------------------------------------------
__global__ __launch_bounds__(THREADS) void k_in_contract(
    const float* __restrict__ x,
    const float* __restrict__ f3, const float* __restrict__ f4,
    const float* __restrict__ f5,
    unsigned short* __restrict__ u3b, int N)
{
    const int n = blockIdx.x;
    const int t = threadIdx.x;

    __shared__ float fs[256];        // f3 [0..128) | f4 [128..256)
    __shared__ float u1s[256 * 9];   // [de][n6], pad 9 -> 2-way max
    __shared__ float u2s[128 * 9];   // [d*8+m][n6], pad 9

    if (t < 128) { fs[t] = f3[t]; fs[128 + t] = f4[t]; }

    float xv[16];
    {
        const float4* xr = (const float4*)(x + (size_t)n * 4096 + t * 16);
        float4 a0 = xr[0], a1 = xr[1], a2 = xr[2], a3 = xr[3];
        xv[0]=a0.x; xv[1]=a0.y; xv[2]=a0.z; xv[3]=a0.w;
        xv[4]=a1.x; xv[5]=a1.y; xv[6]=a1.z; xv[7]=a1.w;
        xv[8]=a2.x; xv[9]=a2.y; xv[10]=a2.z; xv[11]=a2.w;
        xv[12]=a3.x; xv[13]=a3.y; xv[14]=a3.z; xv[15]=a3.w;
    }

    float acc8[8];
    #pragma unroll
    for (int q = 0; q < 8; ++q) acc8[q] = 0.f;
    #pragma unroll
    for (int f = 0; f < 16; ++f) {
        const float xf = xv[f];
        #pragma unroll
        for (int n6 = 0; n6 < 8; ++n6)
            acc8[n6] = fmaf(xf, f5[f*8 + n6], acc8[n6]);
    }
    __syncthreads();
    #pragma unroll
    for (int n6 = 0; n6 < 8; ++n6) u1s[t*9 + n6] = acc8[n6];
    __syncthreads();

    {
        const int d = t >> 4, m = (t >> 1) & 7, h = t & 1;
        float fr[16];
        #pragma unroll
        for (int e = 0; e < 16; ++e) fr[e] = fs[128 + e*8 + m];
        float a4[4] = {0.f, 0.f, 0.f, 0.f};
        #pragma unroll
        for (int e = 0; e < 16; ++e) {
            const int base = (d*16 + e)*9 + h*4;
            #pragma unroll
            for (int q = 0; q < 4; ++q)
                a4[q] = fmaf(u1s[base + q], fr[e], a4[q]);
        }
        #pragma unroll
        for (int q = 0; q < 4; ++q) u2s[(d*8 + m)*9 + h*4 + q] = a4[q];
    }
    __syncthreads();

    {
        const int l = t >> 5, m = (t >> 2) & 7, h = t & 3;
        float fr[16];
        #pragma unroll
        for (int d = 0; d < 16; ++d) fr[d] = fs[d*8 + l];
        float a2[2] = {0.f, 0.f};
        #pragma unroll
        for (int d = 0; d < 16; ++d) {
            const int base = (d*8 + m)*9 + h*2;
            a2[0] = fmaf(u2s[base],     fr[d], a2[0]);
            a2[1] = fmaf(u2s[base + 1], fr[d], a2[1]);
        }
        unsigned int pk = (unsigned int)f2bf(a2[0]) |
                          ((unsigned int)f2bf(a2[1]) << 16);
        ((unsigned int*)u3b)[(size_t)n * 256 + t] = pk;
    }
}

// ---------------------------------------------------------------------------
// core fp32 [512,512] -> bf16. (EXACT round-0 proven version)
// ---------------------------------------------------------------------------
__global__ __launch_bounds__(THREADS) void k_convert_core(
    const float* __restrict__ core, unsigned short* __restrict__ coreb)
{
    const int i = blockIdx.x * THREADS + threadIdx.x;
    float4 c = ((const float4*)core)[i];
    ushort4 o;
    o.x = f2bf(c.x); o.y = f2bf(c.y); o.z = f2bf(c.z); o.w = f2bf(c.w);
    ((ushort4*)coreb)[i] = o;
}

// ---------------------------------------------------------------------------
// Kernel B: MFMA GEMM (EXACT round-0 proven version).
//   v[n,p] = sum_q u3[n,q] * core[p,q]
//   Wave tile 32x32 (2x2 of 16x16x32 bf16). Block = 4 waves stacked in m.
//   Grid (4096/128, 512/32) = (32,16) = 512 blocks.
// ---------------------------------------------------------------------------
__global__ __launch_bounds__(THREADS) void k_core_gemm_mfma(
    const unsigned short* __restrict__ u3b,
    const unsigned short* __restrict__ coreb,
    float* __restrict__ v, int N)
{
    const int t    = threadIdx.x;
    const int lane = t & 63;
    const int wave = t >> 6;
    const int m0 = blockIdx.x * 128 + wave * 32;
    const int p0 = blockIdx.y * 32;
    const int lr = lane & 15;
    const int lq = lane >> 4;

    const unsigned short* aptr0 = u3b   + (size_t)(m0 + lr) * 512 + lq * 8;
    const unsigned short* aptr1 = aptr0 + 16 * 512;
    const unsigned short* bptr0 = coreb + (size_t)(p0 + lr) * 512 + lq * 8;
    const unsigned short* bptr1 = bptr0 + 16 * 512;

    f32x4 acc00 = {0.f,0.f,0.f,0.f}, acc01 = {0.f,0.f,0.f,0.f};
    f32x4 acc10 = {0.f,0.f,0.f,0.f}, acc11 = {0.f,0.f,0.f,0.f};

    #pragma unroll
    for (int k0 = 0; k0 < 512; k0 += 32) {
        bf16x8 a0 = *(const bf16x8*)(aptr0 + k0);
        bf16x8 a1 = *(const bf16x8*)(aptr1 + k0);
        bf16x8 b0 = *(const bf16x8*)(bptr0 + k0);
        bf16x8 b1 = *(const bf16x8*)(bptr1 + k0);
        acc00 = __builtin_amdgcn_mfma_f32_16x16x32_bf16(a0, b0, acc00, 0, 0, 0);
        acc01 = __builtin_amdgcn_mfma_f32_16x16x32_bf16(a0, b1, acc01, 0, 0, 0);
        acc10 = __builtin_amdgcn_mfma_f32_16x16x32_bf16(a1, b0, acc10, 0, 0, 0);
        acc11 = __builtin_amdgcn_mfma_f32_16x16x32_bf16(a1, b1, acc11, 0, 0, 0);
    }

    const int row = m0 + lq * 4;
    const int col = p0 + lr;
    #pragma unroll
    for (int r = 0; r < 4; ++r) {
        v[(size_t)(row + r) * 512 + col]           = acc00[r];
        v[(size_t)(row + r) * 512 + col + 16]      = acc01[r];
        v[(size_t)(row + 16 + r) * 512 + col]      = acc10[r];
        v[(size_t)(row + 16 + r) * 512 + col + 16] = acc11[r];
    }
}

// ---------------------------------------------------------------------------
// Kernel C: out-side expansion — round-0 version MINUS the dead w2s stage.
//   The old w2s LDS round-trip had producer thread == consumer thread
//   ((a,b) identity), so w2 stays in registers; one __syncthreads and
//   256*9*4B of LDS traffic per block removed. This exact transform ran
//   inside round-1's passing fused kernel (same math, verified).
// ---------------------------------------------------------------------------
__global__ __launch_bounds__(THREADS) void k_out_expand(
    const float* __restrict__ v,
    const float* __restrict__ f0, const float* __restrict__ f1,
    const float* __restrict__ f2, const float* __restrict__ bias,
    float* __restrict__ y, int N)
{
    const int n = blockIdx.x;
    const int t = threadIdx.x;

    __shared__ float fs[256];        // f0 [0..128) | f1 [128..256)
    __shared__ float vs[512];
    __shared__ float w1s[128 * 9];   // [a*8+j][k], pad 9

    if (t < 128) { fs[t] = f0[t]; fs[128 + t] = f1[t]; }
    if (t < 128) ((float4*)vs)[t] = ((const float4*)(v + (size_t)n*512))[t];
    __syncthreads();

    // w1 stage: thread -> (a = t>>4, j = (t>>1)&7, h = t&1), k = 4h..4h+3
    {
        const int a = t >> 4, j = (t >> 1) & 7, h = t & 1;
        float fr[8];
        #pragma unroll
        for (int i = 0; i < 8; ++i) fr[i] = fs[a*8 + i];
        float a4[4] = {0.f, 0.f, 0.f, 0.f};
        #pragma unroll
        for (int i = 0; i < 8; ++i) {
            const int base = i*64 + j*8 + h*4;
            #pragma unroll
            for (int q = 0; q < 4; ++q)
                a4[q] = fmaf(vs[base + q], fr[i], a4[q]);
        }
        #pragma unroll
        for (int q = 0; q < 4; ++q) w1s[(a*8 + j)*9 + h*4 + q] = a4[q];
    }
    __syncthreads();

    // w2 (in regs) + y stage: thread -> (a = t>>4, b = t&15), c = 0..15
    {
        const int a = t >> 4, b = t & 15;
        float fr[8];
        #pragma unroll
        for (int j = 0; j < 8; ++j) fr[j] = fs[128 + b*8 + j];
        float w2[8] = {0.f,0.f,0.f,0.f,0.f,0.f,0.f,0.f};
        #pragma unroll
        for (int j = 0; j < 8; ++j) {
            const int base = (a*8 + j)*9;
            const float fj = fr[j];
            #pragma unroll
            for (int k = 0; k < 8; ++k)
                w2[k] = fmaf(w1s[base + k], fj, w2[k]);
        }

        const int obase = a*256 + b*16;   // == t*16
        float4 b4[4];
        {
            const float4* bp = (const float4*)(bias + obase);
            b4[0] = bp[0]; b4[1] = bp[1]; b4[2] = bp[2]; b4[3] = bp[3];
        }
        float yv[16];
        #pragma unroll
        for (int q = 0; q < 4; ++q) {
            yv[q*4+0] = b4[q].x; yv[q*4+1] = b4[q].y;
            yv[q*4+2] = b4[q].z; yv[q*4+3] = b4[q].w;
        }
        #pragma unroll
        for (int c = 0; c < 16; ++c) {
            float s = yv[c];
            #pragma unroll
            for (int k = 0; k < 8; ++k)
                s = fmaf(w2[k], f2[c*8 + k], s);   // f2 lane-uniform -> s_load
            yv[c] = s;
        }
        float4* o = (float4*)(y + (size_t)n*4096 + obase);
        #pragma unroll
        for (int q = 0; q < 4; ++q)
            o[q] = make_float4(yv[q*4+0], yv[q*4+1], yv[q*4+2], yv[q*4+3]);
    }
}

// ---------------------------------------------------------------------------
extern "C" void kernel_launch(void* const* d_in, const int* in_sizes, int n_in,
                              void* d_out, int out_size, void* d_ws, size_t ws_size,
                              hipStream_t stream)
{
    const float* x    = (const float*)d_in[0];
    const float* core = (const float*)d_in[1];
    const float* f0   = (const float*)d_in[2];
    const float* f1   = (const float*)d_in[3];
    const float* f2   = (const float*)d_in[4];
    const float* f3   = (const float*)d_in[5];
    const float* f4   = (const float*)d_in[6];
    const float* f5   = (const float*)d_in[7];
    const float* bias = (const float*)d_in[8];
    float* y = (float*)d_out;

    const int N = in_sizes[0] / 4096;

    // workspace: u3b bf16 [N,512] (4MB) | coreb bf16 [512,512] (0.5MB)
    //          | v fp32 [N,512] (8MB)
    unsigned short* u3b   = (unsigned short*)d_ws;
    unsigned short* coreb = u3b + (size_t)N * 512;
    float*          v     = (float*)(coreb + 512 * 512);

    k_in_contract<<<N, THREADS, 0, stream>>>(x, f3, f4, f5, u3b, N);
    k_convert_core<<<256, THREADS, 0, stream>>>(core, coreb);
    dim3 gb(N / 128, 512 / 32);
    k_core_gemm_mfma<<<gb, THREADS, 0, stream>>>(u3b, coreb, v, N);
    k_out_expand<<<N, THREADS, 0, stream>>>(v, f0, f1, f2, bias, y, N);
}